// Round 1
// baseline (4207.203 us; speedup 1.0000x reference)
//
#include <hip/hip_runtime.h>
#include <hip/hip_bf16.h>

#define N_NODES 50000
#define N_EDGES 800000
#define D 128           // D_IN == D_OUT == 128
#define KCHEB 3

// h[row, :] = x[row, :] @ W  (W is 128x128, read from global/L2; x tile staged in LDS)
// Block: 256 threads, tile = 32 rows x 128 cols, each thread 4 rows x 4 cols.
__global__ __launch_bounds__(256) void gemm_xw(const float* __restrict__ x,
                                               const float* __restrict__ W,
                                               float* __restrict__ h, int n) {
    __shared__ float xlds[32][D];
    const int t = threadIdx.x;
    const int row0 = blockIdx.x * 32;

    // load x tile: 32 rows * 128 = 4096 floats = 1024 float4, 4 per thread
    {
        const float4* xg = (const float4*)x;
        float4* xs = (float4*)&xlds[0][0];
        #pragma unroll
        for (int i = 0; i < 4; ++i) {
            int idx = t + 256 * i;        // float4 index in tile; local row = idx>>5
            int r = row0 + (idx >> 5);
            xs[idx] = (r < n) ? xg[(size_t)r * 32 + (idx & 31)]
                              : make_float4(0.f, 0.f, 0.f, 0.f);
        }
    }
    __syncthreads();

    const int tr = (t >> 5) * 4;          // local row base (0..28)
    const int c0 = (t & 31) * 4;          // col base
    const float4* Wg = (const float4*)W;  // row-major [128][128] -> 32 float4/row

    float acc[4][4] = {};
    #pragma unroll 4
    for (int kk = 0; kk < D; ++kk) {
        float4 wv = Wg[kk * 32 + (c0 >> 2)];   // L2-resident, coalesced/broadcast
        #pragma unroll
        for (int r = 0; r < 4; ++r) {
            float xv = xlds[tr + r][kk];       // wave-uniform per 32-lane group
            acc[r][0] += xv * wv.x;
            acc[r][1] += xv * wv.y;
            acc[r][2] += xv * wv.z;
            acc[r][3] += xv * wv.w;
        }
    }

    #pragma unroll
    for (int r = 0; r < 4; ++r) {
        int gr = row0 + tr + r;
        if (gr < n) {
            float4 v = make_float4(acc[r][0], acc[r][1], acc[r][2], acc[r][3]);
            *(float4*)&h[(size_t)gr * D + c0] = v;
        }
    }
}

// out[dst[e], :] += h[src[e], :] * w[e].  32 lanes per edge, float4 per lane.
__global__ __launch_bounds__(256) void scatter_edges(const float* __restrict__ h,
                                                     const int* __restrict__ src,
                                                     const int* __restrict__ dst,
                                                     const float* __restrict__ w,
                                                     float* __restrict__ out) {
    const int gid = blockIdx.x * 256 + threadIdx.x;
    const int e = gid >> 5;          // grid sized exactly: e < N_EDGES
    const int l = gid & 31;

    const int s = src[e];
    const int d = dst[e];
    const float ww = w[e];

    float4 v = *(const float4*)&h[(size_t)s * D + l * 4];
    float* op = &out[(size_t)d * D + l * 4];
    atomicAdd(op + 0, v.x * ww);
    atomicAdd(op + 1, v.y * ww);
    atomicAdd(op + 2, v.z * ww);
    atomicAdd(op + 3, v.w * ww);
}

extern "C" void kernel_launch(void* const* d_in, const int* in_sizes, int n_in,
                              void* d_out, int out_size, void* d_ws, size_t ws_size,
                              hipStream_t stream) {
    const float* x  = (const float*)d_in[0];              // [N, 128]
    const float* W  = (const float*)d_in[1];              // [K, 128, 128]
    const int*   ei = (const int*)d_in[2];                // [K, 2, E]
    const float* ew = (const float*)d_in[3];              // [K, E]
    float* out = (float*)d_out;                           // [N, 128]
    float* h = (float*)d_ws;                              // [N, 128] scratch (25.6 MB)

    // d_out is poisoned with 0xAA before every call — zero it.
    hipMemsetAsync(out, 0, (size_t)N_NODES * D * sizeof(float), stream);

    const int gemm_grid = (N_NODES + 31) / 32;            // 1563
    const int scat_grid = (N_EDGES * 32) / 256;           // 100000

    for (int k = 0; k < KCHEB; ++k) {
        const float* Wk  = W + (size_t)k * D * D;
        const int*   srk = ei + (size_t)k * 2 * N_EDGES;
        const int*   dsk = srk + N_EDGES;
        const float* ewk = ew + (size_t)k * N_EDGES;

        gemm_xw<<<gemm_grid, 256, 0, stream>>>(x, Wk, h, N_NODES);
        scatter_edges<<<scat_grid, 256, 0, stream>>>(h, srk, dsk, ewk, out);
    }
}

// Round 2
// 697.472 us; speedup vs baseline: 6.0321x; 6.0321x over previous
//
#include <hip/hip_runtime.h>
#include <hip/hip_bf16.h>

#define N_NODES 50000
#define N_EDGES 800000
#define D 128           // D_IN == D_OUT == 128
#define KCHEB 3
#define M_CNT (KCHEB * N_NODES)                          // 150000 (k,node) counters
#define SCAN_CHUNK 1024
#define NB_SCAN ((M_CNT + SCAN_CHUNK - 1) / SCAN_CHUNK)  // 147

// ---------------- dense GEMM: h = x @ W_k (fp32, vector ALU) ----------------
__global__ __launch_bounds__(256) void gemm_xw(const float* __restrict__ x,
                                               const float* __restrict__ W,
                                               float* __restrict__ h, int n) {
    __shared__ float xlds[32][D];
    const int t = threadIdx.x;
    const int row0 = blockIdx.x * 32;

    {
        const float4* xg = (const float4*)x;
        float4* xs = (float4*)&xlds[0][0];
        #pragma unroll
        for (int i = 0; i < 4; ++i) {
            int idx = t + 256 * i;
            int r = row0 + (idx >> 5);
            xs[idx] = (r < n) ? xg[(size_t)r * 32 + (idx & 31)]
                              : make_float4(0.f, 0.f, 0.f, 0.f);
        }
    }
    __syncthreads();

    const int tr = (t >> 5) * 4;
    const int c0 = (t & 31) * 4;
    const float4* Wg = (const float4*)W;

    float acc[4][4] = {};
    #pragma unroll 4
    for (int kk = 0; kk < D; ++kk) {
        float4 wv = Wg[kk * 32 + (c0 >> 2)];
        #pragma unroll
        for (int r = 0; r < 4; ++r) {
            float xv = xlds[tr + r][kk];
            acc[r][0] += xv * wv.x;
            acc[r][1] += xv * wv.y;
            acc[r][2] += xv * wv.z;
            acc[r][3] += xv * wv.w;
        }
    }

    #pragma unroll
    for (int r = 0; r < 4; ++r) {
        int gr = row0 + tr + r;
        if (gr < n) {
            float4 v = make_float4(acc[r][0], acc[r][1], acc[r][2], acc[r][3]);
            *(float4*)&h[(size_t)gr * D + c0] = v;
        }
    }
}

// ---------------- counting sort: histogram over dst ----------------
__global__ __launch_bounds__(256) void hist_dst(const int* __restrict__ ei,
                                                int* __restrict__ counts) {
    int e = blockIdx.x * 256 + threadIdx.x;
    int k = blockIdx.y;
    if (e >= N_EDGES) return;
    int dst = ei[(size_t)k * 2 * N_EDGES + N_EDGES + e];
    atomicAdd(&counts[k * N_NODES + dst], 1);
}

// ---------------- exclusive scan over 150k counters (3 small kernels) ----------------
__global__ __launch_bounds__(256) void scan_blocks(const int* __restrict__ counts,
                                                   int* __restrict__ offsets,
                                                   int* __restrict__ blockSums) {
    const int t = threadIdx.x;
    const int lane = t & 63, wid = t >> 6;
    const int i0 = blockIdx.x * SCAN_CHUNK + t * 4;
    int c0 = (i0 + 0 < M_CNT) ? counts[i0 + 0] : 0;
    int c1 = (i0 + 1 < M_CNT) ? counts[i0 + 1] : 0;
    int c2 = (i0 + 2 < M_CNT) ? counts[i0 + 2] : 0;
    int c3 = (i0 + 3 < M_CNT) ? counts[i0 + 3] : 0;
    int tsum = c0 + c1 + c2 + c3;

    int v = tsum;                       // wave-64 inclusive scan
    #pragma unroll
    for (int d = 1; d < 64; d <<= 1) {
        int u = __shfl_up(v, d, 64);
        if (lane >= d) v += u;
    }
    __shared__ int wsum[4];
    if (lane == 63) wsum[wid] = v;
    __syncthreads();
    int base = 0;
    for (int i = 0; i < wid; ++i) base += wsum[i];

    int excl = base + v - tsum;         // exclusive prefix of this thread's 1st elem
    if (i0 + 0 < M_CNT) offsets[i0 + 0] = excl;
    if (i0 + 1 < M_CNT) offsets[i0 + 1] = excl + c0;
    if (i0 + 2 < M_CNT) offsets[i0 + 2] = excl + c0 + c1;
    if (i0 + 3 < M_CNT) offsets[i0 + 3] = excl + c0 + c1 + c2;
    if (t == 255) blockSums[blockIdx.x] = base + v;   // block total
}

__global__ __launch_bounds__(256) void scan_sums(int* __restrict__ blockSums) {
    __shared__ int s[256];
    const int t = threadIdx.x;
    s[t] = (t < NB_SCAN) ? blockSums[t] : 0;
    __syncthreads();
    if (t == 0) {
        int run = 0;
        for (int i = 0; i < NB_SCAN; ++i) { int c = s[i]; s[i] = run; run += c; }
    }
    __syncthreads();
    if (t < NB_SCAN) blockSums[t] = s[t];
}

__global__ __launch_bounds__(256) void add_base(int* __restrict__ offsets,
                                                const int* __restrict__ blockSums) {
    int i = blockIdx.x * 256 + threadIdx.x;
    if (i < M_CNT) offsets[i] += blockSums[i >> 10];          // SCAN_CHUNK = 1024
    else if (i == M_CNT) offsets[M_CNT] = KCHEB * N_EDGES;    // sentinel
}

// ---------------- reorder edges into CSR (consumes counts as cursor) ----------------
__global__ __launch_bounds__(256) void reorder_edges(const int* __restrict__ ei,
                                                     const float* __restrict__ ew,
                                                     const int* __restrict__ offsets,
                                                     int* __restrict__ cursor,
                                                     int2* __restrict__ csr) {
    int e = blockIdx.x * 256 + threadIdx.x;
    int k = blockIdx.y;
    if (e >= N_EDGES) return;
    int src = ei[(size_t)k * 2 * N_EDGES + e];
    int dst = ei[(size_t)k * 2 * N_EDGES + N_EDGES + e];
    float w = ew[(size_t)k * N_EDGES + e];
    int kd = k * N_NODES + dst;
    int r = atomicSub(&cursor[kd], 1) - 1;                    // cnt-1 .. 0
    csr[offsets[kd] + r] = make_int2(src, __float_as_int(w));
}

// ---------------- gather: one wave per node, accumulate in registers ----------------
__global__ __launch_bounds__(256) void gather_nodes(const float* __restrict__ h,
                                                    const int2* __restrict__ csr,
                                                    const int* __restrict__ offsets,
                                                    float* __restrict__ out, int k) {
    const int wid = threadIdx.x >> 6;
    const int lane = threadIdx.x & 63;
    const int node = blockIdx.x * 4 + wid;
    if (node >= N_NODES) return;
    const int kd = k * N_NODES + node;
    const int off = offsets[kd];
    const int end = offsets[kd + 1];

    float2 acc = make_float2(0.f, 0.f);
    for (int i = off; i < end; ++i) {
        int2 e = csr[i];                                      // same-addr broadcast
        float w = __int_as_float(e.y);
        float2 v = *(const float2*)&h[(size_t)e.x * D + lane * 2];
        acc.x += w * v.x;
        acc.y += w * v.y;
    }
    float2* op = (float2*)&out[(size_t)node * D + lane * 2];
    if (k == 0) {
        *op = acc;                                            // also zeroes cnt==0 rows
    } else {
        float2 p = *op;
        p.x += acc.x; p.y += acc.y;
        *op = p;
    }
}

extern "C" void kernel_launch(void* const* d_in, const int* in_sizes, int n_in,
                              void* d_out, int out_size, void* d_ws, size_t ws_size,
                              hipStream_t stream) {
    const float* x  = (const float*)d_in[0];              // [N, 128]
    const float* W  = (const float*)d_in[1];              // [K, 128, 128]
    const int*   ei = (const int*)d_in[2];                // [K, 2, E]
    const float* ew = (const float*)d_in[3];              // [K, E]
    float* out = (float*)d_out;                           // [N, 128]

    // workspace layout (bytes):
    char* ws = (char*)d_ws;
    float* h         = (float*)(ws);                      // 25,600,000
    int2*  csr       = (int2*) (ws + 25600000);           // 19,200,000
    int*   counts    = (int*)  (ws + 44800000);           //    600,000
    int*   offsets   = (int*)  (ws + 45400000);           //    600,016 (M_CNT+1, padded)
    int*   blockSums = (int*)  (ws + 46000016);           //      1,024

    hipMemsetAsync(counts, 0, (size_t)M_CNT * sizeof(int), stream);

    const dim3 egrid((N_EDGES + 255) / 256, KCHEB);       // (3125, 3)
    hist_dst<<<egrid, 256, 0, stream>>>(ei, counts);
    scan_blocks<<<NB_SCAN, 256, 0, stream>>>(counts, offsets, blockSums);
    scan_sums<<<1, 256, 0, stream>>>(blockSums);
    add_base<<<(M_CNT + 1 + 255) / 256, 256, 0, stream>>>(offsets, blockSums);
    reorder_edges<<<egrid, 256, 0, stream>>>(ei, ew, offsets, counts, csr);

    const int gemm_grid = (N_NODES + 31) / 32;            // 1563
    const int gat_grid  = (N_NODES + 3) / 4;              // 12500
    for (int k = 0; k < KCHEB; ++k) {
        const float* Wk = W + (size_t)k * D * D;
        gemm_xw<<<gemm_grid, 256, 0, stream>>>(x, Wk, h, N_NODES);
        gather_nodes<<<gat_grid, 256, 0, stream>>>(h, csr, offsets, out, k);
    }
}

// Round 3
// 395.313 us; speedup vs baseline: 10.6427x; 1.7644x over previous
//
#include <hip/hip_runtime.h>
#include <hip/hip_bf16.h>

#define N_NODES 50000
#define N_EDGES 800000
#define D 128
#define KCHEB 3
#define M_CNT (KCHEB * N_NODES)        // 150000 (k,node) segments
#define NBKT 98                        // buckets per k: node range 512 (50000>>9 -> 0..97)
#define TOTB (KCHEB * NBKT)            // 294
#define EPB 4096                       // edges per block in binning passes
#define NBLK_E ((N_EDGES + EPB - 1) / EPB)   // 196

__device__ inline unsigned f2bf(float f) {   // fp32 -> bf16 bits, round-nearest-even
    unsigned x = __float_as_uint(f);
    unsigned r = ((x >> 16) & 1u) + 0x7FFFu;
    return (x + r) >> 16;
}

// ---------------- GEMM: h_bf16 = x @ W_k ----------------
__global__ __launch_bounds__(256) void gemm_xw(const float* __restrict__ x,
                                               const float* __restrict__ W,
                                               unsigned* __restrict__ h2, int n) {
    __shared__ float xlds[32][D];
    const int t = threadIdx.x;
    const int row0 = blockIdx.x * 32;
    {
        const float4* xg = (const float4*)x;
        float4* xs = (float4*)&xlds[0][0];
        #pragma unroll
        for (int i = 0; i < 4; ++i) {
            int idx = t + 256 * i;
            int r = row0 + (idx >> 5);
            xs[idx] = (r < n) ? xg[(size_t)r * 32 + (idx & 31)]
                              : make_float4(0.f, 0.f, 0.f, 0.f);
        }
    }
    __syncthreads();

    const int tr = (t >> 5) * 4;
    const int c0 = (t & 31) * 4;
    const float4* Wg = (const float4*)W;

    float acc[4][4] = {};
    #pragma unroll 4
    for (int kk = 0; kk < D; ++kk) {
        float4 wv = Wg[kk * 32 + (c0 >> 2)];
        #pragma unroll
        for (int r = 0; r < 4; ++r) {
            float xv = xlds[tr + r][kk];
            acc[r][0] += xv * wv.x;
            acc[r][1] += xv * wv.y;
            acc[r][2] += xv * wv.z;
            acc[r][3] += xv * wv.w;
        }
    }
    #pragma unroll
    for (int r = 0; r < 4; ++r) {
        int gr = row0 + tr + r;
        if (gr < n) {
            unsigned p0 = f2bf(acc[r][0]) | (f2bf(acc[r][1]) << 16);
            unsigned p1 = f2bf(acc[r][2]) | (f2bf(acc[r][3]) << 16);
            *(uint2*)&h2[(size_t)gr * 64 + (c0 >> 1)] = make_uint2(p0, p1);
        }
    }
}

// ---------------- Pass A0: per-(k,bucket) edge counts ----------------
__global__ __launch_bounds__(256) void bucket_count(const int* __restrict__ ei,
                                                    int* __restrict__ bktCnt) {
    __shared__ int lh[NBKT];
    const int k = blockIdx.y, t = threadIdx.x;
    for (int i = t; i < NBKT; i += 256) lh[i] = 0;
    __syncthreads();
    const int* dsts = ei + (size_t)k * 2 * N_EDGES + N_EDGES;
    const int base = blockIdx.x * EPB;
    for (int i = t; i < EPB; i += 256) {
        int e = base + i;
        if (e < N_EDGES) atomicAdd(&lh[dsts[e] >> 9], 1);
    }
    __syncthreads();
    for (int i = t; i < NBKT; i += 256)
        if (lh[i]) atomicAdd(&bktCnt[k * NBKT + i], lh[i]);
}

// ---------------- tiny scan over 294 bucket counts ----------------
__global__ void scan_buckets(const int* __restrict__ bktCnt, int* __restrict__ bktBase,
                             int* __restrict__ bktCursor, int* __restrict__ offsets) {
    if (threadIdx.x == 0) {
        int run = 0;
        for (int i = 0; i < TOTB; ++i) {
            bktBase[i] = run; bktCursor[i] = run; run += bktCnt[i];
        }
        bktBase[TOTB] = run;           // 2.4M
        offsets[M_CNT] = run;          // global sentinel
    }
}

// ---------------- Pass A: bin edges by (k, dst>>9) ----------------
__global__ __launch_bounds__(256) void bucket_bin(const int* __restrict__ ei,
                                                  const float* __restrict__ ew,
                                                  int* __restrict__ bktCursor,
                                                  uint2* __restrict__ binned) {
    __shared__ int lh[NBKT], gb[NBKT], lc[NBKT];
    const int k = blockIdx.y, t = threadIdx.x;
    for (int i = t; i < NBKT; i += 256) { lh[i] = 0; lc[i] = 0; }
    __syncthreads();
    const int* srcs = ei + (size_t)k * 2 * N_EDGES;
    const int* dsts = srcs + N_EDGES;
    const float* w = ew + (size_t)k * N_EDGES;
    const int base = blockIdx.x * EPB;
    for (int i = t; i < EPB; i += 256) {
        int e = base + i;
        if (e < N_EDGES) atomicAdd(&lh[dsts[e] >> 9], 1);
    }
    __syncthreads();
    for (int i = t; i < NBKT; i += 256)
        gb[i] = lh[i] ? atomicAdd(&bktCursor[k * NBKT + i], lh[i]) : 0;
    __syncthreads();
    for (int i = t; i < EPB; i += 256) {
        int e = base + i;
        if (e >= N_EDGES) continue;
        int d = dsts[e];
        int b = d >> 9;
        int pos = gb[b] + atomicAdd(&lc[b], 1);
        // src fits 16 bits (50000 < 65536); dst-local 9 bits at [16,25)
        binned[pos] = make_uint2(__float_as_uint(w[e]),
                                 (unsigned)srcs[e] | ((unsigned)(d & 511) << 16));
    }
}

// ---------------- Pass B: per-bucket CSR build (LDS hist + scan + scatter) ----------------
__global__ __launch_bounds__(256) void build_csr(const uint2* __restrict__ binned,
                                                 const int* __restrict__ bktBase,
                                                 int* __restrict__ offsets,
                                                 int2* __restrict__ csr) {
    __shared__ int nh[512], ex[512], wsum[4];
    const int kb = blockIdx.x;
    const int k = kb / NBKT, b = kb % NBKT;
    const int t = threadIdx.x;
    const int beg = bktBase[kb], end = bktBase[kb + 1];

    for (int i = t; i < 512; i += 256) nh[i] = 0;
    __syncthreads();
    for (int i = beg + t; i < end; i += 256)
        atomicAdd(&nh[(binned[i].y >> 16) & 511], 1);
    __syncthreads();

    // exclusive scan of nh[512]; each thread owns elements 2t, 2t+1
    int a0 = nh[2 * t], a1 = nh[2 * t + 1];
    int s = a0 + a1;
    int lane = t & 63, wid = t >> 6;
    int v = s;
    #pragma unroll
    for (int d = 1; d < 64; d <<= 1) {
        int u = __shfl_up(v, d, 64);
        if (lane >= d) v += u;
    }
    if (lane == 63) wsum[wid] = v;
    __syncthreads();
    int wb = 0;
    for (int i = 0; i < wid; ++i) wb += wsum[i];
    int ep = wb + v - s;
    ex[2 * t] = ep;
    ex[2 * t + 1] = ep + a0;
    __syncthreads();

    const int node0 = b * 512;
    for (int i = t; i < 512; i += 256) {
        int node = node0 + i;
        if (node < N_NODES) offsets[k * N_NODES + node] = beg + ex[i];
    }
    for (int i = t; i < 512; i += 256) nh[i] = 0;   // reuse as cursor
    __syncthreads();
    for (int i = beg + t; i < end; i += 256) {
        uint2 e = binned[i];
        int dl = (e.y >> 16) & 511;
        int pos = beg + ex[dl] + atomicAdd(&nh[dl], 1);
        csr[pos] = make_int2((int)(e.y & 0xFFFFu), (int)e.x);
    }
}

// ---------------- gather: one wave per node, bf16 h, 4-deep pipelined ----------------
__global__ __launch_bounds__(256) void gather_nodes(const unsigned* __restrict__ h2,
                                                    const int2* __restrict__ csr,
                                                    const int* __restrict__ offsets,
                                                    float* __restrict__ out, int k) {
    const int wid = threadIdx.x >> 6;
    const int lane = threadIdx.x & 63;
    const int node = blockIdx.x * 4 + wid;
    if (node >= N_NODES) return;
    const int kd = k * N_NODES + node;
    int i = offsets[kd];
    const int end = offsets[kd + 1];

    float ax = 0.f, ay = 0.f;
    for (; i + 4 <= end; i += 4) {
        int2 e0 = csr[i], e1 = csr[i + 1], e2 = csr[i + 2], e3 = csr[i + 3];
        unsigned u0 = h2[(size_t)e0.x * 64 + lane];
        unsigned u1 = h2[(size_t)e1.x * 64 + lane];
        unsigned u2 = h2[(size_t)e2.x * 64 + lane];
        unsigned u3 = h2[(size_t)e3.x * 64 + lane];
        float w0 = __int_as_float(e0.y), w1 = __int_as_float(e1.y);
        float w2 = __int_as_float(e2.y), w3 = __int_as_float(e3.y);
        ax += w0 * __uint_as_float(u0 << 16);
        ay += w0 * __uint_as_float(u0 & 0xFFFF0000u);
        ax += w1 * __uint_as_float(u1 << 16);
        ay += w1 * __uint_as_float(u1 & 0xFFFF0000u);
        ax += w2 * __uint_as_float(u2 << 16);
        ay += w2 * __uint_as_float(u2 & 0xFFFF0000u);
        ax += w3 * __uint_as_float(u3 << 16);
        ay += w3 * __uint_as_float(u3 & 0xFFFF0000u);
    }
    for (; i < end; ++i) {
        int2 e = csr[i];
        float w = __int_as_float(e.y);
        unsigned u = h2[(size_t)e.x * 64 + lane];
        ax += w * __uint_as_float(u << 16);
        ay += w * __uint_as_float(u & 0xFFFF0000u);
    }
    float2* op = (float2*)&out[(size_t)node * D + lane * 2];
    if (k == 0) {
        *op = make_float2(ax, ay);
    } else {
        float2 p = *op;
        *op = make_float2(p.x + ax, p.y + ay);
    }
}

extern "C" void kernel_launch(void* const* d_in, const int* in_sizes, int n_in,
                              void* d_out, int out_size, void* d_ws, size_t ws_size,
                              hipStream_t stream) {
    const float* x  = (const float*)d_in[0];
    const float* W  = (const float*)d_in[1];
    const int*   ei = (const int*)d_in[2];
    const float* ew = (const float*)d_in[3];
    float* out = (float*)d_out;

    // workspace layout (bytes); binned is dead after build_csr, h2 aliases it
    char* ws = (char*)d_ws;
    int2*     csr       = (int2*)    (ws);                  // 19,200,000
    uint2*    binned    = (uint2*)   (ws + 19200000);       // 19,200,000
    unsigned* h2        = (unsigned*)(ws + 19200000);       // 12,800,000 (aliases binned)
    int*      offsets   = (int*)     (ws + 38400000);       // 600,004 (M_CNT+1)
    int*      bktCnt    = (int*)     (ws + 39000008);       // 1,176
    int*      bktBase   = (int*)     (ws + 39001184);       // 1,180 (TOTB+1)
    int*      bktCursor = (int*)     (ws + 39002368);       // 1,176

    hipMemsetAsync(bktCnt, 0, TOTB * sizeof(int), stream);

    const dim3 egrid(NBLK_E, KCHEB);                        // (196, 3)
    bucket_count<<<egrid, 256, 0, stream>>>(ei, bktCnt);
    scan_buckets<<<1, 64, 0, stream>>>(bktCnt, bktBase, bktCursor, offsets);
    bucket_bin<<<egrid, 256, 0, stream>>>(ei, ew, bktCursor, binned);
    build_csr<<<TOTB, 256, 0, stream>>>(binned, bktBase, offsets, csr);

    const int gemm_grid = (N_NODES + 31) / 32;              // 1563
    const int gat_grid  = (N_NODES + 3) / 4;                // 12500
    for (int k = 0; k < KCHEB; ++k) {
        const float* Wk = W + (size_t)k * D * D;
        gemm_xw<<<gemm_grid, 256, 0, stream>>>(x, Wk, h2, N_NODES);
        gather_nodes<<<gat_grid, 256, 0, stream>>>(h2, csr, offsets, out, k);
    }
}

// Round 4
// 348.524 us; speedup vs baseline: 12.0715x; 1.1342x over previous
//
#include <hip/hip_runtime.h>
#include <hip/hip_bf16.h>

#define N_NODES 50000
#define N_EDGES 800000
#define D 128
#define KCHEB 3
#define M_CNT (KCHEB * N_NODES)        // 150000 (k,node) segments
#define NBKT 98                        // buckets per k: node range 512
#define TOTB (KCHEB * NBKT)            // 294
#define EPB 4096
#define NBLK_E ((N_EDGES + EPB - 1) / EPB)   // 196

typedef __attribute__((ext_vector_type(8))) short short8v;   // 8 bf16 (4 VGPRs)
typedef __attribute__((ext_vector_type(4))) float f32x4;

__device__ inline unsigned f2bf(float f) {   // fp32 -> bf16 bits, round-nearest-even
    unsigned x = __float_as_uint(f);
    unsigned r = ((x >> 16) & 1u) + 0x7FFFu;
    return (x + r) >> 16;
}

// ---------------- MFMA GEMM: h_bf16 = x @ W_k ----------------
// block = 256 thr (4 waves), BM=64 rows, N=128, K=128.
// Wt = W_k^T in LDS as bf16, XOR-swizzled; A-frags straight from global fp32 x.
__global__ __launch_bounds__(256) void gemm_mfma(const float* __restrict__ x,
                                                 const float* __restrict__ W,
                                                 unsigned* __restrict__ h2, int n) {
    __shared__ unsigned short Wt[128 * 128];          // 32 KB, [n][k] swizzled
    const int t = threadIdx.x;

    // load W (row-major [k][n] fp32), convert, store transposed+swizzled
    #pragma unroll 4
    for (int i = 0; i < 16; ++i) {
        int linear = i * 256 + t;                     // 0..4095 (float4 units)
        int r  = linear >> 5;                         // k index 0..127
        int c4 = (linear & 31) * 4;                   // n index base
        float4 wv = *(const float4*)&W[r * 128 + c4];
        #pragma unroll
        for (int j = 0; j < 4; ++j) {
            int row = c4 + j;                         // Wt row = n
            int byte_in_row = (r * 2) ^ ((row & 7) << 4);
            Wt[row * 128 + (byte_in_row >> 1)] = (unsigned short)f2bf((&wv.x)[j]);
        }
    }
    __syncthreads();

    const int lane = t & 63, w = t >> 6;
    const int m0 = blockIdx.x * 64 + w * 16;
    const int arow = m0 + (lane & 15);
    const float* xr = x + (size_t)(arow < n ? arow : 0) * D + ((lane >> 4) << 3);

    // A-fragments: 4 k-tiles, 8 contiguous k each: k = kt*32 + (lane>>4)*8 + j
    short8v afr[4];
    #pragma unroll
    for (int kt = 0; kt < 4; ++kt) {
        float4 p0 = *(const float4*)(xr + kt * 32);
        float4 p1 = *(const float4*)(xr + kt * 32 + 4);
        union { short8v s; unsigned u[4]; } a;
        a.u[0] = f2bf(p0.x) | (f2bf(p0.y) << 16);
        a.u[1] = f2bf(p0.z) | (f2bf(p0.w) << 16);
        a.u[2] = f2bf(p1.x) | (f2bf(p1.y) << 16);
        a.u[3] = f2bf(p1.z) | (f2bf(p1.w) << 16);
        afr[kt] = a.s;
    }

    f32x4 acc[8] = {};
    const int kb = (lane >> 4) << 4;                  // byte offset of lane's k-block
    #pragma unroll
    for (int nn = 0; nn < 8; ++nn) {
        const int row = nn * 16 + (lane & 15);        // Wt row (n index)
        const int sw = (row & 7) << 4;
        const unsigned short* wr = &Wt[row * 128];
        #pragma unroll
        for (int kt = 0; kt < 4; ++kt) {
            int byte_in_row = ((kt << 6) + kb) ^ sw;
            short8v b = *(const short8v*)&wr[byte_in_row >> 1];
            acc[nn] = __builtin_amdgcn_mfma_f32_16x16x32_bf16(afr[kt], b, acc[nn], 0, 0, 0);
        }
    }

    // C/D layout: col = lane&15, row = (lane>>4)*4 + reg
    unsigned short* hs = (unsigned short*)h2;
    const int orow_base = m0 + ((lane >> 4) << 2);
    const int col_base = lane & 15;
    #pragma unroll
    for (int nn = 0; nn < 8; ++nn) {
        int col = nn * 16 + col_base;
        #pragma unroll
        for (int r = 0; r < 4; ++r) {
            int orow = orow_base + r;
            if (orow < n) hs[(size_t)orow * D + col] = (unsigned short)f2bf(acc[nn][r]);
        }
    }
}

// ---------------- Pass A0: per-(k,bucket) edge counts ----------------
__global__ __launch_bounds__(256) void bucket_count(const int* __restrict__ ei,
                                                    int* __restrict__ bktCnt) {
    __shared__ int lh[NBKT];
    const int k = blockIdx.y, t = threadIdx.x;
    for (int i = t; i < NBKT; i += 256) lh[i] = 0;
    __syncthreads();
    const int* dsts = ei + (size_t)k * 2 * N_EDGES + N_EDGES;
    const int base = blockIdx.x * EPB;
    for (int i = t; i < EPB; i += 256) {
        int e = base + i;
        if (e < N_EDGES) atomicAdd(&lh[dsts[e] >> 9], 1);
    }
    __syncthreads();
    for (int i = t; i < NBKT; i += 256)
        if (lh[i]) atomicAdd(&bktCnt[k * NBKT + i], lh[i]);
}

// ---------------- tiny scan over 294 bucket counts ----------------
__global__ void scan_buckets(const int* __restrict__ bktCnt, int* __restrict__ bktBase,
                             int* __restrict__ bktCursor, int* __restrict__ offsets) {
    if (threadIdx.x == 0) {
        int run = 0;
        for (int i = 0; i < TOTB; ++i) {
            bktBase[i] = run; bktCursor[i] = run; run += bktCnt[i];
        }
        bktBase[TOTB] = run;
        offsets[M_CNT] = run;
    }
}

// ---------------- Pass A: bin edges by (k, dst>>9) ----------------
__global__ __launch_bounds__(256) void bucket_bin(const int* __restrict__ ei,
                                                  const float* __restrict__ ew,
                                                  int* __restrict__ bktCursor,
                                                  uint2* __restrict__ binned) {
    __shared__ int lh[NBKT], gb[NBKT], lc[NBKT];
    const int k = blockIdx.y, t = threadIdx.x;
    for (int i = t; i < NBKT; i += 256) { lh[i] = 0; lc[i] = 0; }
    __syncthreads();
    const int* srcs = ei + (size_t)k * 2 * N_EDGES;
    const int* dsts = srcs + N_EDGES;
    const float* w = ew + (size_t)k * N_EDGES;
    const int base = blockIdx.x * EPB;
    for (int i = t; i < EPB; i += 256) {
        int e = base + i;
        if (e < N_EDGES) atomicAdd(&lh[dsts[e] >> 9], 1);
    }
    __syncthreads();
    for (int i = t; i < NBKT; i += 256)
        gb[i] = lh[i] ? atomicAdd(&bktCursor[k * NBKT + i], lh[i]) : 0;
    __syncthreads();
    for (int i = t; i < EPB; i += 256) {
        int e = base + i;
        if (e >= N_EDGES) continue;
        int d = dsts[e];
        int b = d >> 9;
        int pos = gb[b] + atomicAdd(&lc[b], 1);
        binned[pos] = make_uint2(__float_as_uint(w[e]),
                                 (unsigned)srcs[e] | ((unsigned)(d & 511) << 16));
    }
}

// ---------------- Pass B: per-bucket CSR build ----------------
__global__ __launch_bounds__(256) void build_csr(const uint2* __restrict__ binned,
                                                 const int* __restrict__ bktBase,
                                                 int* __restrict__ offsets,
                                                 int2* __restrict__ csr) {
    __shared__ int nh[512], ex[512], wsum[4];
    const int kb = blockIdx.x;
    const int k = kb / NBKT, b = kb % NBKT;
    const int t = threadIdx.x;
    const int beg = bktBase[kb], end = bktBase[kb + 1];

    for (int i = t; i < 512; i += 256) nh[i] = 0;
    __syncthreads();
    for (int i = beg + t; i < end; i += 256)
        atomicAdd(&nh[(binned[i].y >> 16) & 511], 1);
    __syncthreads();

    int a0 = nh[2 * t], a1 = nh[2 * t + 1];
    int s = a0 + a1;
    int lane = t & 63, wid = t >> 6;
    int v = s;
    #pragma unroll
    for (int d = 1; d < 64; d <<= 1) {
        int u = __shfl_up(v, d, 64);
        if (lane >= d) v += u;
    }
    if (lane == 63) wsum[wid] = v;
    __syncthreads();
    int wb = 0;
    for (int i = 0; i < wid; ++i) wb += wsum[i];
    int ep = wb + v - s;
    ex[2 * t] = ep;
    ex[2 * t + 1] = ep + a0;
    __syncthreads();

    const int node0 = b * 512;
    for (int i = t; i < 512; i += 256) {
        int node = node0 + i;
        if (node < N_NODES) offsets[k * N_NODES + node] = beg + ex[i];
    }
    for (int i = t; i < 512; i += 256) nh[i] = 0;
    __syncthreads();
    for (int i = beg + t; i < end; i += 256) {
        uint2 e = binned[i];
        int dl = (e.y >> 16) & 511;
        int pos = beg + ex[dl] + atomicAdd(&nh[dl], 1);
        csr[pos] = make_int2((int)(e.y & 0xFFFFu), (int)e.x);
    }
}

// ---------------- gather: one wave per node, bf16 h, 4-deep pipelined ----------------
__global__ __launch_bounds__(256) void gather_nodes(const unsigned* __restrict__ h2,
                                                    const int2* __restrict__ csr,
                                                    const int* __restrict__ offsets,
                                                    float* __restrict__ out, int k) {
    const int wid = threadIdx.x >> 6;
    const int lane = threadIdx.x & 63;
    const int node = blockIdx.x * 4 + wid;
    if (node >= N_NODES) return;
    const int kd = k * N_NODES + node;
    int i = offsets[kd];
    const int end = offsets[kd + 1];

    float ax = 0.f, ay = 0.f;
    for (; i + 4 <= end; i += 4) {
        int2 e0 = csr[i], e1 = csr[i + 1], e2 = csr[i + 2], e3 = csr[i + 3];
        unsigned u0 = h2[(size_t)e0.x * 64 + lane];
        unsigned u1 = h2[(size_t)e1.x * 64 + lane];
        unsigned u2 = h2[(size_t)e2.x * 64 + lane];
        unsigned u3 = h2[(size_t)e3.x * 64 + lane];
        float w0 = __int_as_float(e0.y), w1 = __int_as_float(e1.y);
        float w2 = __int_as_float(e2.y), w3 = __int_as_float(e3.y);
        ax += w0 * __uint_as_float(u0 << 16);
        ay += w0 * __uint_as_float(u0 & 0xFFFF0000u);
        ax += w1 * __uint_as_float(u1 << 16);
        ay += w1 * __uint_as_float(u1 & 0xFFFF0000u);
        ax += w2 * __uint_as_float(u2 << 16);
        ay += w2 * __uint_as_float(u2 & 0xFFFF0000u);
        ax += w3 * __uint_as_float(u3 << 16);
        ay += w3 * __uint_as_float(u3 & 0xFFFF0000u);
    }
    for (; i < end; ++i) {
        int2 e = csr[i];
        float w = __int_as_float(e.y);
        unsigned u = h2[(size_t)e.x * 64 + lane];
        ax += w * __uint_as_float(u << 16);
        ay += w * __uint_as_float(u & 0xFFFF0000u);
    }
    float2* op = (float2*)&out[(size_t)node * D + lane * 2];
    if (k == 0) {
        *op = make_float2(ax, ay);
    } else {
        float2 p = *op;
        *op = make_float2(p.x + ax, p.y + ay);
    }
}

extern "C" void kernel_launch(void* const* d_in, const int* in_sizes, int n_in,
                              void* d_out, int out_size, void* d_ws, size_t ws_size,
                              hipStream_t stream) {
    const float* x  = (const float*)d_in[0];
    const float* W  = (const float*)d_in[1];
    const int*   ei = (const int*)d_in[2];
    const float* ew = (const float*)d_in[3];
    float* out = (float*)d_out;

    char* ws = (char*)d_ws;
    int2*     csr       = (int2*)    (ws);                  // 19,200,000
    uint2*    binned    = (uint2*)   (ws + 19200000);       // 19,200,000
    unsigned* h2        = (unsigned*)(ws + 19200000);       // 12,800,000 (aliases binned)
    int*      offsets   = (int*)     (ws + 38400000);       // 600,004
    int*      bktCnt    = (int*)     (ws + 39000008);
    int*      bktBase   = (int*)     (ws + 39001184);
    int*      bktCursor = (int*)     (ws + 39002368);

    hipMemsetAsync(bktCnt, 0, TOTB * sizeof(int), stream);

    const dim3 egrid(NBLK_E, KCHEB);
    bucket_count<<<egrid, 256, 0, stream>>>(ei, bktCnt);
    scan_buckets<<<1, 64, 0, stream>>>(bktCnt, bktBase, bktCursor, offsets);
    bucket_bin<<<egrid, 256, 0, stream>>>(ei, ew, bktCursor, binned);
    build_csr<<<TOTB, 256, 0, stream>>>(binned, bktBase, offsets, csr);

    const int gemm_grid = (N_NODES + 63) / 64;              // 782
    const int gat_grid  = (N_NODES + 3) / 4;                // 12500
    for (int k = 0; k < KCHEB; ++k) {
        const float* Wk = W + (size_t)k * D * D;
        gemm_mfma<<<gemm_grid, 256, 0, stream>>>(x, Wk, h2, N_NODES);
        gather_nodes<<<gat_grid, 256, 0, stream>>>(h2, csr, offsets, out, k);
    }
}

// Round 5
// 338.195 us; speedup vs baseline: 12.4402x; 1.0305x over previous
//
#include <hip/hip_runtime.h>
#include <hip/hip_bf16.h>

#define N_NODES 50000
#define N_EDGES 800000
#define D 128
#define KCHEB 3
#define M_CNT (KCHEB * N_NODES)        // 150000 (k,node) segments
#define NBKT 98                        // buckets per k: node range 512
#define TOTB (KCHEB * NBKT)            // 294
#define EPB 2048
#define NBLK_E ((N_EDGES + EPB - 1) / EPB)   // 391

typedef __attribute__((ext_vector_type(8))) short short8v;   // 8 bf16 (4 VGPRs)
typedef __attribute__((ext_vector_type(4))) float f32x4;

__device__ inline unsigned f2bf(float f) {   // fp32 -> bf16 bits, round-nearest-even
    unsigned x = __float_as_uint(f);
    unsigned r = ((x >> 16) & 1u) + 0x7FFFu;
    return (x + r) >> 16;
}

// ---------------- MFMA GEMM: h_bf16 = x @ W_k ----------------
__global__ __launch_bounds__(256) void gemm_mfma(const float* __restrict__ x,
                                                 const float* __restrict__ W,
                                                 unsigned* __restrict__ h2, int n) {
    __shared__ unsigned short Wt[128 * 128];          // 32 KB, [n][k] swizzled
    const int t = threadIdx.x;

    #pragma unroll 4
    for (int i = 0; i < 16; ++i) {
        int linear = i * 256 + t;                     // float4 units
        int r  = linear >> 5;                         // k index
        int c4 = (linear & 31) * 4;                   // n index base
        float4 wv = *(const float4*)&W[r * 128 + c4];
        #pragma unroll
        for (int j = 0; j < 4; ++j) {
            int row = c4 + j;
            int byte_in_row = (r * 2) ^ ((row & 7) << 4);
            Wt[row * 128 + (byte_in_row >> 1)] = (unsigned short)f2bf((&wv.x)[j]);
        }
    }
    __syncthreads();

    const int lane = t & 63, w = t >> 6;
    const int m0 = blockIdx.x * 64 + w * 16;
    const int arow = m0 + (lane & 15);
    const float* xr = x + (size_t)(arow < n ? arow : 0) * D + ((lane >> 4) << 3);

    short8v afr[4];
    #pragma unroll
    for (int kt = 0; kt < 4; ++kt) {
        float4 p0 = *(const float4*)(xr + kt * 32);
        float4 p1 = *(const float4*)(xr + kt * 32 + 4);
        union { short8v s; unsigned u[4]; } a;
        a.u[0] = f2bf(p0.x) | (f2bf(p0.y) << 16);
        a.u[1] = f2bf(p0.z) | (f2bf(p0.w) << 16);
        a.u[2] = f2bf(p1.x) | (f2bf(p1.y) << 16);
        a.u[3] = f2bf(p1.z) | (f2bf(p1.w) << 16);
        afr[kt] = a.s;
    }

    f32x4 acc[8] = {};
    const int kb = (lane >> 4) << 4;
    #pragma unroll
    for (int nn = 0; nn < 8; ++nn) {
        const int row = nn * 16 + (lane & 15);
        const int sw = (row & 7) << 4;
        const unsigned short* wr = &Wt[row * 128];
        #pragma unroll
        for (int kt = 0; kt < 4; ++kt) {
            int byte_in_row = ((kt << 6) + kb) ^ sw;
            short8v b = *(const short8v*)&wr[byte_in_row >> 1];
            acc[nn] = __builtin_amdgcn_mfma_f32_16x16x32_bf16(afr[kt], b, acc[nn], 0, 0, 0);
        }
    }

    unsigned short* hs = (unsigned short*)h2;
    const int orow_base = m0 + ((lane >> 4) << 2);
    const int col_base = lane & 15;
    #pragma unroll
    for (int nn = 0; nn < 8; ++nn) {
        int col = nn * 16 + col_base;
        #pragma unroll
        for (int r = 0; r < 4; ++r) {
            int orow = orow_base + r;
            if (orow < n) hs[(size_t)orow * D + col] = (unsigned short)f2bf(acc[nn][r]);
        }
    }
}

// ---------------- Pass A0: per-(k,bucket) edge counts (int4-vectorized) ----------------
__global__ __launch_bounds__(256) void bucket_count(const int* __restrict__ ei,
                                                    int* __restrict__ bktCnt) {
    __shared__ int lh[NBKT];
    const int k = blockIdx.y, t = threadIdx.x;
    for (int i = t; i < NBKT; i += 256) lh[i] = 0;
    __syncthreads();
    const int* dsts = ei + (size_t)k * 2 * N_EDGES + N_EDGES;
    const int base = blockIdx.x * EPB;
    #pragma unroll
    for (int q = 0; q < EPB / 1024; ++q) {        // 4 edges/thread/iter, N_EDGES%4==0
        int e = base + q * 1024 + t * 4;
        if (e < N_EDGES) {
            int4 d4 = *(const int4*)&dsts[e];
            atomicAdd(&lh[d4.x >> 9], 1);
            atomicAdd(&lh[d4.y >> 9], 1);
            atomicAdd(&lh[d4.z >> 9], 1);
            atomicAdd(&lh[d4.w >> 9], 1);
        }
    }
    __syncthreads();
    for (int i = t; i < NBKT; i += 256)
        if (lh[i]) atomicAdd(&bktCnt[k * NBKT + i], lh[i]);
}

// ---------------- tiny scan over 294 bucket counts ----------------
__global__ void scan_buckets(const int* __restrict__ bktCnt, int* __restrict__ bktBase,
                             int* __restrict__ bktCursor, int* __restrict__ offsets) {
    if (threadIdx.x == 0) {
        int run = 0;
        for (int i = 0; i < TOTB; ++i) {
            bktBase[i] = run; bktCursor[i] = run; run += bktCnt[i];
        }
        bktBase[TOTB] = run;
        offsets[M_CNT] = run;
    }
}

// ---------------- Pass A: bin edges by (k, dst>>9) (vectorized) ----------------
__global__ __launch_bounds__(256) void bucket_bin(const int* __restrict__ ei,
                                                  const float* __restrict__ ew,
                                                  int* __restrict__ bktCursor,
                                                  uint2* __restrict__ binned) {
    __shared__ int lh[NBKT], gb[NBKT], lc[NBKT];
    const int k = blockIdx.y, t = threadIdx.x;
    for (int i = t; i < NBKT; i += 256) { lh[i] = 0; lc[i] = 0; }
    __syncthreads();
    const int* srcs = ei + (size_t)k * 2 * N_EDGES;
    const int* dsts = srcs + N_EDGES;
    const float* w = ew + (size_t)k * N_EDGES;
    const int base = blockIdx.x * EPB;
    #pragma unroll
    for (int q = 0; q < EPB / 1024; ++q) {
        int e = base + q * 1024 + t * 4;
        if (e < N_EDGES) {
            int4 d4 = *(const int4*)&dsts[e];
            atomicAdd(&lh[d4.x >> 9], 1);
            atomicAdd(&lh[d4.y >> 9], 1);
            atomicAdd(&lh[d4.z >> 9], 1);
            atomicAdd(&lh[d4.w >> 9], 1);
        }
    }
    __syncthreads();
    for (int i = t; i < NBKT; i += 256)
        gb[i] = lh[i] ? atomicAdd(&bktCursor[k * NBKT + i], lh[i]) : 0;
    __syncthreads();
    #pragma unroll
    for (int q = 0; q < EPB / 1024; ++q) {
        int e = base + q * 1024 + t * 4;
        if (e < N_EDGES) {
            int4 d4 = *(const int4*)&dsts[e];
            int4 s4 = *(const int4*)&srcs[e];
            float4 w4 = *(const float4*)&w[e];
            #pragma unroll
            for (int j = 0; j < 4; ++j) {
                int d = (&d4.x)[j];
                int b = d >> 9;
                int pos = gb[b] + atomicAdd(&lc[b], 1);
                binned[pos] = make_uint2(__float_as_uint((&w4.x)[j]),
                                         (unsigned)(&s4.x)[j] | ((unsigned)(d & 511) << 16));
            }
        }
    }
}

// ---------------- Pass B: per-bucket CSR build ----------------
__global__ __launch_bounds__(256) void build_csr(const uint2* __restrict__ binned,
                                                 const int* __restrict__ bktBase,
                                                 int* __restrict__ offsets,
                                                 int2* __restrict__ csr) {
    __shared__ int nh[512], ex[512], wsum[4];
    const int kb = blockIdx.x;
    const int k = kb / NBKT, b = kb % NBKT;
    const int t = threadIdx.x;
    const int beg = bktBase[kb], end = bktBase[kb + 1];

    for (int i = t; i < 512; i += 256) nh[i] = 0;
    __syncthreads();
    for (int i = beg + t; i < end; i += 256)
        atomicAdd(&nh[(binned[i].y >> 16) & 511], 1);
    __syncthreads();

    int a0 = nh[2 * t], a1 = nh[2 * t + 1];
    int s = a0 + a1;
    int lane = t & 63, wid = t >> 6;
    int v = s;
    #pragma unroll
    for (int d = 1; d < 64; d <<= 1) {
        int u = __shfl_up(v, d, 64);
        if (lane >= d) v += u;
    }
    if (lane == 63) wsum[wid] = v;
    __syncthreads();
    int wb = 0;
    for (int i = 0; i < wid; ++i) wb += wsum[i];
    int ep = wb + v - s;
    ex[2 * t] = ep;
    ex[2 * t + 1] = ep + a0;
    __syncthreads();

    const int node0 = b * 512;
    for (int i = t; i < 512; i += 256) {
        int node = node0 + i;
        if (node < N_NODES) offsets[k * N_NODES + node] = beg + ex[i];
    }
    for (int i = t; i < 512; i += 256) nh[i] = 0;
    __syncthreads();
    for (int i = beg + t; i < end; i += 256) {
        uint2 e = binned[i];
        int dl = (e.y >> 16) & 511;
        int pos = beg + ex[dl] + atomicAdd(&nh[dl], 1);
        csr[pos] = make_int2((int)(e.y & 0xFFFFu), (int)e.x);
    }
}

// ---------------- merged gather: one wave per node, all 3 k's, out written once ----------------
__global__ __launch_bounds__(256) void gather_all(const unsigned* __restrict__ h3,
                                                  const int2* __restrict__ csr,
                                                  const int* __restrict__ offsets,
                                                  float* __restrict__ out) {
    const int wid = threadIdx.x >> 6;
    const int lane = threadIdx.x & 63;
    const int node = blockIdx.x * 4 + wid;
    if (node >= N_NODES) return;

    float ax = 0.f, ay = 0.f;
    #pragma unroll
    for (int k = 0; k < KCHEB; ++k) {
        const unsigned* h2 = h3 + (size_t)k * N_NODES * 64;
        const int kd = k * N_NODES + node;
        int i = offsets[kd];
        const int end = offsets[kd + 1];
        for (; i + 4 <= end; i += 4) {
            int2 e0 = csr[i], e1 = csr[i + 1], e2 = csr[i + 2], e3 = csr[i + 3];
            unsigned u0 = h2[(size_t)e0.x * 64 + lane];
            unsigned u1 = h2[(size_t)e1.x * 64 + lane];
            unsigned u2 = h2[(size_t)e2.x * 64 + lane];
            unsigned u3 = h2[(size_t)e3.x * 64 + lane];
            float w0 = __int_as_float(e0.y), w1 = __int_as_float(e1.y);
            float w2 = __int_as_float(e2.y), w3 = __int_as_float(e3.y);
            ax += w0 * __uint_as_float(u0 << 16);
            ay += w0 * __uint_as_float(u0 & 0xFFFF0000u);
            ax += w1 * __uint_as_float(u1 << 16);
            ay += w1 * __uint_as_float(u1 & 0xFFFF0000u);
            ax += w2 * __uint_as_float(u2 << 16);
            ay += w2 * __uint_as_float(u2 & 0xFFFF0000u);
            ax += w3 * __uint_as_float(u3 << 16);
            ay += w3 * __uint_as_float(u3 & 0xFFFF0000u);
        }
        for (; i < end; ++i) {
            int2 e = csr[i];
            float w = __int_as_float(e.y);
            unsigned u = h2[(size_t)e.x * 64 + lane];
            ax += w * __uint_as_float(u << 16);
            ay += w * __uint_as_float(u & 0xFFFF0000u);
        }
    }
    *(float2*)&out[(size_t)node * D + lane * 2] = make_float2(ax, ay);
}

extern "C" void kernel_launch(void* const* d_in, const int* in_sizes, int n_in,
                              void* d_out, int out_size, void* d_ws, size_t ws_size,
                              hipStream_t stream) {
    const float* x  = (const float*)d_in[0];
    const float* W  = (const float*)d_in[1];
    const int*   ei = (const int*)d_in[2];
    const float* ew = (const float*)d_in[3];
    float* out = (float*)d_out;

    // workspace layout (bytes) — ws_size = 256 MiB (observed via harness poison fill)
    char* ws = (char*)d_ws;
    int2*     csr       = (int2*)    (ws);                  // 19,200,000
    uint2*    binned    = (uint2*)   (ws + 19200000);       // 19,200,000
    unsigned* h3        = (unsigned*)(ws + 38400000);       // 38,400,000 (3 x bf16 [N,128])
    int*      offsets   = (int*)     (ws + 76800000);       // 600,004
    int*      bktCnt    = (int*)     (ws + 77400064);       // 1,176
    int*      bktBase   = (int*)     (ws + 77401248);       // 1,180
    int*      bktCursor = (int*)     (ws + 77402432);       // 1,176

    hipMemsetAsync(bktCnt, 0, TOTB * sizeof(int), stream);

    const dim3 egrid(NBLK_E, KCHEB);                        // (391, 3)
    bucket_count<<<egrid, 256, 0, stream>>>(ei, bktCnt);
    scan_buckets<<<1, 64, 0, stream>>>(bktCnt, bktBase, bktCursor, offsets);
    bucket_bin<<<egrid, 256, 0, stream>>>(ei, ew, bktCursor, binned);
    build_csr<<<TOTB, 256, 0, stream>>>(binned, bktBase, offsets, csr);

    const int gemm_grid = (N_NODES + 63) / 64;              // 782
    for (int k = 0; k < KCHEB; ++k)
        gemm_mfma<<<gemm_grid, 256, 0, stream>>>(x, W + (size_t)k * D * D,
                                                 h3 + (size_t)k * N_NODES * 64, N_NODES);

    const int gat_grid = (N_NODES + 3) / 4;                 // 12500
    gather_all<<<gat_grid, 256, 0, stream>>>(h3, csr, offsets, out);
}

// Round 6
// 296.908 us; speedup vs baseline: 14.1701x; 1.1391x over previous
//
#include <hip/hip_runtime.h>
#include <hip/hip_bf16.h>

#define N_NODES 50000
#define N_EDGES 800000
#define D 128
#define KCHEB 3
#define M_CNT (KCHEB * N_NODES)        // 150000 (k,node) segments
#define NBKT 98                        // buckets per k: node range 512
#define TOTB (KCHEB * NBKT)            // 294
#define SLAB 16384                     // slab capacity (edges) per bucket; expected ~8163
#define EPB 2048
#define NBLK_E ((N_EDGES + EPB - 1) / EPB)   // 391

typedef __attribute__((ext_vector_type(8))) short short8v;   // 8 bf16 (4 VGPRs)
typedef __attribute__((ext_vector_type(4))) float f32x4;

__device__ inline unsigned f2bf(float f) {   // fp32 -> bf16 bits, round-nearest-even
    unsigned x = __float_as_uint(f);
    unsigned r = ((x >> 16) & 1u) + 0x7FFFu;
    return (x + r) >> 16;
}

// ---------------- MFMA GEMM: h_bf16[k] = x @ W_k  (gridDim.y = k) ----------------
__global__ __launch_bounds__(256) void gemm_mfma(const float* __restrict__ x,
                                                 const float* __restrict__ Wall,
                                                 unsigned* __restrict__ h3, int n) {
    __shared__ unsigned short Wt[128 * 128];          // 32 KB, [n][k] swizzled
    const int t = threadIdx.x;
    const float* W = Wall + (size_t)blockIdx.y * D * D;
    unsigned* h2 = h3 + (size_t)blockIdx.y * N_NODES * 64;

    #pragma unroll 4
    for (int i = 0; i < 16; ++i) {
        int linear = i * 256 + t;                     // float4 units
        int r  = linear >> 5;                         // k index
        int c4 = (linear & 31) * 4;                   // n index base
        float4 wv = *(const float4*)&W[r * 128 + c4];
        #pragma unroll
        for (int j = 0; j < 4; ++j) {
            int row = c4 + j;
            int byte_in_row = (r * 2) ^ ((row & 7) << 4);
            Wt[row * 128 + (byte_in_row >> 1)] = (unsigned short)f2bf((&wv.x)[j]);
        }
    }
    __syncthreads();

    const int lane = t & 63, w = t >> 6;
    const int m0 = blockIdx.x * 64 + w * 16;
    const int arow = m0 + (lane & 15);
    const float* xr = x + (size_t)(arow < n ? arow : 0) * D + ((lane >> 4) << 3);

    short8v afr[4];
    #pragma unroll
    for (int kt = 0; kt < 4; ++kt) {
        float4 p0 = *(const float4*)(xr + kt * 32);
        float4 p1 = *(const float4*)(xr + kt * 32 + 4);
        union { short8v s; unsigned u[4]; } a;
        a.u[0] = f2bf(p0.x) | (f2bf(p0.y) << 16);
        a.u[1] = f2bf(p0.z) | (f2bf(p0.w) << 16);
        a.u[2] = f2bf(p1.x) | (f2bf(p1.y) << 16);
        a.u[3] = f2bf(p1.z) | (f2bf(p1.w) << 16);
        afr[kt] = a.s;
    }

    f32x4 acc[8] = {};
    const int kb = (lane >> 4) << 4;
    #pragma unroll
    for (int nn = 0; nn < 8; ++nn) {
        const int row = nn * 16 + (lane & 15);
        const int sw = (row & 7) << 4;
        const unsigned short* wr = &Wt[row * 128];
        #pragma unroll
        for (int kt = 0; kt < 4; ++kt) {
            int byte_in_row = ((kt << 6) + kb) ^ sw;
            short8v b = *(const short8v*)&wr[byte_in_row >> 1];
            acc[nn] = __builtin_amdgcn_mfma_f32_16x16x32_bf16(afr[kt], b, acc[nn], 0, 0, 0);
        }
    }

    unsigned short* hs = (unsigned short*)h2;
    const int orow_base = m0 + ((lane >> 4) << 2);
    const int col_base = lane & 15;
    #pragma unroll
    for (int nn = 0; nn < 8; ++nn) {
        int col = nn * 16 + col_base;
        #pragma unroll
        for (int r = 0; r < 4; ++r) {
            int orow = orow_base + r;
            if (orow < n) hs[(size_t)orow * D + col] = (unsigned short)f2bf(acc[nn][r]);
        }
    }
}

// ---------------- bin edges by (k, dst>>9) into fixed slabs (no pre-count) ----------------
__global__ __launch_bounds__(256) void bucket_bin(const int* __restrict__ ei,
                                                  const float* __restrict__ ew,
                                                  int* __restrict__ cursor,
                                                  uint2* __restrict__ binned) {
    __shared__ int lh[NBKT], gb[NBKT], lc[NBKT];
    const int k = blockIdx.y, t = threadIdx.x;
    for (int i = t; i < NBKT; i += 256) { lh[i] = 0; lc[i] = 0; }
    __syncthreads();
    const int* srcs = ei + (size_t)k * 2 * N_EDGES;
    const int* dsts = srcs + N_EDGES;
    const float* w = ew + (size_t)k * N_EDGES;
    const int base = blockIdx.x * EPB;
    #pragma unroll
    for (int q = 0; q < EPB / 1024; ++q) {
        int e = base + q * 1024 + t * 4;
        if (e < N_EDGES) {
            int4 d4 = *(const int4*)&dsts[e];
            atomicAdd(&lh[d4.x >> 9], 1);
            atomicAdd(&lh[d4.y >> 9], 1);
            atomicAdd(&lh[d4.z >> 9], 1);
            atomicAdd(&lh[d4.w >> 9], 1);
        }
    }
    __syncthreads();
    for (int i = t; i < NBKT; i += 256)
        gb[i] = lh[i] ? atomicAdd(&cursor[k * NBKT + i], lh[i]) : 0;   // slab-local base
    __syncthreads();
    #pragma unroll
    for (int q = 0; q < EPB / 1024; ++q) {
        int e = base + q * 1024 + t * 4;
        if (e < N_EDGES) {
            int4 d4 = *(const int4*)&dsts[e];
            int4 s4 = *(const int4*)&srcs[e];
            float4 w4 = *(const float4*)&w[e];
            #pragma unroll
            for (int j = 0; j < 4; ++j) {
                int d = (&d4.x)[j];
                int b = d >> 9;
                int pos = (k * NBKT + b) * SLAB + gb[b] + atomicAdd(&lc[b], 1);
                binned[pos] = make_uint2(__float_as_uint((&w4.x)[j]),
                                         (unsigned)(&s4.x)[j] | ((unsigned)(d & 511) << 16));
            }
        }
    }
}

// ---------------- per-bucket CSR build into csr slab; emit off[]/num[] ----------------
__global__ __launch_bounds__(256) void build_csr(const uint2* __restrict__ binned,
                                                 const int* __restrict__ cursor,
                                                 int* __restrict__ off,
                                                 int* __restrict__ num,
                                                 int2* __restrict__ csr) {
    __shared__ int nh[512], ex[512], wsum[4];
    const int kb = blockIdx.x;
    const int k = kb / NBKT, b = kb % NBKT;
    const int t = threadIdx.x;
    const int beg = kb * SLAB;
    const int end = beg + cursor[kb];

    for (int i = t; i < 512; i += 256) nh[i] = 0;
    __syncthreads();
    for (int i = beg + t; i < end; i += 256)
        atomicAdd(&nh[(binned[i].y >> 16) & 511], 1);
    __syncthreads();

    int a0 = nh[2 * t], a1 = nh[2 * t + 1];
    int s = a0 + a1;
    int lane = t & 63, wid = t >> 6;
    int v = s;
    #pragma unroll
    for (int d = 1; d < 64; d <<= 1) {
        int u = __shfl_up(v, d, 64);
        if (lane >= d) v += u;
    }
    if (lane == 63) wsum[wid] = v;
    __syncthreads();
    int wb = 0;
    for (int i = 0; i < wid; ++i) wb += wsum[i];
    int ep = wb + v - s;
    ex[2 * t] = ep;
    ex[2 * t + 1] = ep + a0;

    // off/num for the two nodes this thread owns
    const int node0 = b * 512;
    int n0 = node0 + 2 * t, n1 = node0 + 2 * t + 1;
    if (n0 < N_NODES) { off[k * N_NODES + n0] = beg + ep;      num[k * N_NODES + n0] = a0; }
    if (n1 < N_NODES) { off[k * N_NODES + n1] = beg + ep + a0; num[k * N_NODES + n1] = a1; }

    for (int i = t; i < 512; i += 256) nh[i] = 0;   // reuse as cursor
    __syncthreads();
    for (int i = beg + t; i < end; i += 256) {
        uint2 e = binned[i];
        int dl = (e.y >> 16) & 511;
        int pos = beg + ex[dl] + atomicAdd(&nh[dl], 1);
        csr[pos] = make_int2((int)(e.y & 0xFFFFu), (int)e.x);
    }
}

// ---------------- merged gather: one wave per node, all 3 k's, 8-deep pipeline ----------------
__global__ __launch_bounds__(256) void gather_all(const unsigned* __restrict__ h3,
                                                  const int2* __restrict__ csr,
                                                  const int* __restrict__ off,
                                                  const int* __restrict__ num,
                                                  float* __restrict__ out) {
    const int wid = threadIdx.x >> 6;
    const int lane = threadIdx.x & 63;
    const int node = blockIdx.x * 4 + wid;
    if (node >= N_NODES) return;

    float ax = 0.f, ay = 0.f;
    #pragma unroll
    for (int k = 0; k < KCHEB; ++k) {
        const unsigned* h2 = h3 + (size_t)k * N_NODES * 64;
        const int kd = k * N_NODES + node;
        int i = off[kd];
        const int end = i + num[kd];
        for (; i + 8 <= end; i += 8) {
            int2 ed[8];
            unsigned u[8];
            #pragma unroll
            for (int j = 0; j < 8; ++j) ed[j] = csr[i + j];
            #pragma unroll
            for (int j = 0; j < 8; ++j) u[j] = h2[(size_t)ed[j].x * 64 + lane];
            #pragma unroll
            for (int j = 0; j < 8; ++j) {
                float w = __int_as_float(ed[j].y);
                ax += w * __uint_as_float(u[j] << 16);
                ay += w * __uint_as_float(u[j] & 0xFFFF0000u);
            }
        }
        for (; i < end; ++i) {
            int2 e = csr[i];
            float w = __int_as_float(e.y);
            unsigned uu = h2[(size_t)e.x * 64 + lane];
            ax += w * __uint_as_float(uu << 16);
            ay += w * __uint_as_float(uu & 0xFFFF0000u);
        }
    }
    *(float2*)&out[(size_t)node * D + lane * 2] = make_float2(ax, ay);
}

extern "C" void kernel_launch(void* const* d_in, const int* in_sizes, int n_in,
                              void* d_out, int out_size, void* d_ws, size_t ws_size,
                              hipStream_t stream) {
    const float* x  = (const float*)d_in[0];
    const float* W  = (const float*)d_in[1];
    const int*   ei = (const int*)d_in[2];
    const float* ew = (const float*)d_in[3];
    float* out = (float*)d_out;

    // workspace layout (bytes) — ws_size = 256 MiB
    char* ws = (char*)d_ws;
    int2*     csr    = (int2*)    (ws);                     // 294*16384*8 = 38,535,168
    uint2*    binned = (uint2*)   (ws + 38535168);          // 38,535,168
    unsigned* h3     = (unsigned*)(ws + 77070336);          // 38,400,000 (3 x bf16 [N,128])
    int*      off    = (int*)     (ws + 115470336);         // 600,000
    int*      num    = (int*)     (ws + 116070336);         // 600,000
    int*      cursor = (int*)     (ws + 116670336);         // 1,176

    hipMemsetAsync(cursor, 0, TOTB * sizeof(int), stream);

    const dim3 egrid(NBLK_E, KCHEB);                        // (391, 3)
    bucket_bin<<<egrid, 256, 0, stream>>>(ei, ew, cursor, binned);

    const dim3 ggrid((N_NODES + 63) / 64, KCHEB);           // (782, 3)
    gemm_mfma<<<ggrid, 256, 0, stream>>>(x, W, h3, N_NODES);

    build_csr<<<TOTB, 256, 0, stream>>>(binned, cursor, off, num, csr);

    const int gat_grid = (N_NODES + 3) / 4;                 // 12500
    gather_all<<<gat_grid, 256, 0, stream>>>(h3, csr, off, num, out);
}

// Round 7
// 264.483 us; speedup vs baseline: 15.9072x; 1.1226x over previous
//
#include <hip/hip_runtime.h>
#include <hip/hip_bf16.h>

#define N_NODES 50000
#define N_EDGES 800000
#define D 128
#define KCHEB 3
#define NBKT 98                        // buckets per k: node range 512
#define TOTB (KCHEB * NBKT)            // 294
#define SLAB 16384                     // slab capacity (edges) per bucket; expected ~8163
#define EPB 2048
#define NBLK_E ((N_EDGES + EPB - 1) / EPB)   // 391

typedef __attribute__((ext_vector_type(8))) short short8v;   // 8 bf16 (4 VGPRs)
typedef __attribute__((ext_vector_type(4))) float f32x4;

__device__ inline unsigned f2bf(float f) {   // fp32 -> bf16 bits, round-nearest-even
    unsigned x = __float_as_uint(f);
    unsigned r = ((x >> 16) & 1u) + 0x7FFFu;
    return (x + r) >> 16;
}

// ---------------- W prep: fp32 [k][kidx][n] -> bf16 transposed+swizzled [k][n][kidx] ----------------
__global__ __launch_bounds__(256) void wprep(const float* __restrict__ W,
                                             unsigned short* __restrict__ Wtg) {
    const int k = blockIdx.x;
    const float* Wk = W + (size_t)k * D * D;
    unsigned short* o = Wtg + (size_t)k * D * D;
    for (int i = threadIdx.x; i < 4096; i += 256) {   // float4 units
        int r  = i >> 5;                              // kidx
        int c4 = (i & 31) * 4;                        // n base
        float4 wv = *(const float4*)&Wk[r * 128 + c4];
        #pragma unroll
        for (int j = 0; j < 4; ++j) {
            int row = c4 + j;                         // n
            int byte_in_row = (r * 2) ^ ((row & 7) << 4);
            o[row * 128 + (byte_in_row >> 1)] = (unsigned short)f2bf((&wv.x)[j]);
        }
    }
}

// ---------------- MFMA GEMM: h_bf16[k] = x @ W_k  (gridDim.y = k) ----------------
__global__ __launch_bounds__(256) void gemm_mfma(const float* __restrict__ x,
                                                 const unsigned short* __restrict__ Wtg,
                                                 unsigned* __restrict__ h3, int n) {
    __shared__ unsigned short Wt[128 * 128];          // 32 KB, [n][kidx] swizzled
    const int t = threadIdx.x;
    unsigned* h2 = h3 + (size_t)blockIdx.y * N_NODES * 64;

    {   // pure 32 KB copy, already converted/transposed/swizzled
        const uint4* src = (const uint4*)(Wtg + (size_t)blockIdx.y * D * D);
        uint4* dst = (uint4*)Wt;
        #pragma unroll
        for (int i = 0; i < 8; ++i) dst[t + 256 * i] = src[t + 256 * i];
    }
    __syncthreads();

    const int lane = t & 63, w = t >> 6;
    const int m0 = blockIdx.x * 64 + w * 16;
    const int arow = m0 + (lane & 15);
    const float* xr = x + (size_t)(arow < n ? arow : 0) * D + ((lane >> 4) << 3);

    short8v afr[4];
    #pragma unroll
    for (int kt = 0; kt < 4; ++kt) {
        float4 p0 = *(const float4*)(xr + kt * 32);
        float4 p1 = *(const float4*)(xr + kt * 32 + 4);
        union { short8v s; unsigned u[4]; } a;
        a.u[0] = f2bf(p0.x) | (f2bf(p0.y) << 16);
        a.u[1] = f2bf(p0.z) | (f2bf(p0.w) << 16);
        a.u[2] = f2bf(p1.x) | (f2bf(p1.y) << 16);
        a.u[3] = f2bf(p1.z) | (f2bf(p1.w) << 16);
        afr[kt] = a.s;
    }

    f32x4 acc[8] = {};
    const int kb = (lane >> 4) << 4;
    #pragma unroll
    for (int nn = 0; nn < 8; ++nn) {
        const int row = nn * 16 + (lane & 15);
        const int sw = (row & 7) << 4;
        const unsigned short* wr = &Wt[row * 128];
        #pragma unroll
        for (int kt = 0; kt < 4; ++kt) {
            int byte_in_row = ((kt << 6) + kb) ^ sw;
            short8v b = *(const short8v*)&wr[byte_in_row >> 1];
            acc[nn] = __builtin_amdgcn_mfma_f32_16x16x32_bf16(afr[kt], b, acc[nn], 0, 0, 0);
        }
    }

    unsigned short* hs = (unsigned short*)h2;
    const int orow_base = m0 + ((lane >> 4) << 2);
    const int col_base = lane & 15;
    #pragma unroll
    for (int nn = 0; nn < 8; ++nn) {
        int col = nn * 16 + col_base;
        #pragma unroll
        for (int r = 0; r < 4; ++r) {
            int orow = orow_base + r;
            if (orow < n) hs[(size_t)orow * D + col] = (unsigned short)f2bf(acc[nn][r]);
        }
    }
}

// ---------------- bin edges by (k, dst>>9) into fixed slabs ----------------
__global__ __launch_bounds__(256) void bucket_bin(const int* __restrict__ ei,
                                                  const float* __restrict__ ew,
                                                  int* __restrict__ cursor,
                                                  uint2* __restrict__ binned) {
    __shared__ int lh[NBKT], gb[NBKT], lc[NBKT];
    const int k = blockIdx.y, t = threadIdx.x;
    for (int i = t; i < NBKT; i += 256) { lh[i] = 0; lc[i] = 0; }
    __syncthreads();
    const int* srcs = ei + (size_t)k * 2 * N_EDGES;
    const int* dsts = srcs + N_EDGES;
    const float* w = ew + (size_t)k * N_EDGES;
    const int base = blockIdx.x * EPB;
    #pragma unroll
    for (int q = 0; q < EPB / 1024; ++q) {
        int e = base + q * 1024 + t * 4;
        if (e < N_EDGES) {
            int4 d4 = *(const int4*)&dsts[e];
            atomicAdd(&lh[d4.x >> 9], 1);
            atomicAdd(&lh[d4.y >> 9], 1);
            atomicAdd(&lh[d4.z >> 9], 1);
            atomicAdd(&lh[d4.w >> 9], 1);
        }
    }
    __syncthreads();
    for (int i = t; i < NBKT; i += 256)
        gb[i] = lh[i] ? atomicAdd(&cursor[k * NBKT + i], lh[i]) : 0;   // slab-local base
    __syncthreads();
    #pragma unroll
    for (int q = 0; q < EPB / 1024; ++q) {
        int e = base + q * 1024 + t * 4;
        if (e < N_EDGES) {
            int4 d4 = *(const int4*)&dsts[e];
            int4 s4 = *(const int4*)&srcs[e];
            float4 w4 = *(const float4*)&w[e];
            #pragma unroll
            for (int j = 0; j < 4; ++j) {
                int d = (&d4.x)[j];
                int b = d >> 9;
                int pos = (k * NBKT + b) * SLAB + gb[b] + atomicAdd(&lc[b], 1);
                binned[pos] = make_uint2(__float_as_uint((&w4.x)[j]),
                                         (unsigned)(&s4.x)[j] | ((unsigned)(d & 511) << 16));
            }
        }
    }
}

// ---------------- per-bucket CSR build; csr entry = {src:u16 | w_bf16<<16} ----------------
__global__ __launch_bounds__(256) void build_csr(const uint2* __restrict__ binned,
                                                 const int* __restrict__ cursor,
                                                 int* __restrict__ off,
                                                 int* __restrict__ num,
                                                 unsigned* __restrict__ csr4) {
    __shared__ int nh[512], ex[512], wsum[4];
    const int kb = blockIdx.x;
    const int k = kb / NBKT, b = kb % NBKT;
    const int t = threadIdx.x;
    const int beg = kb * SLAB;
    const int end = beg + cursor[kb];

    for (int i = t; i < 512; i += 256) nh[i] = 0;
    __syncthreads();
    for (int i = beg + t; i < end; i += 256)
        atomicAdd(&nh[(binned[i].y >> 16) & 511], 1);
    __syncthreads();

    int a0 = nh[2 * t], a1 = nh[2 * t + 1];
    int s = a0 + a1;
    int lane = t & 63, wid = t >> 6;
    int v = s;
    #pragma unroll
    for (int d = 1; d < 64; d <<= 1) {
        int u = __shfl_up(v, d, 64);
        if (lane >= d) v += u;
    }
    if (lane == 63) wsum[wid] = v;
    __syncthreads();
    int wb = 0;
    for (int i = 0; i < wid; ++i) wb += wsum[i];
    int ep = wb + v - s;
    ex[2 * t] = ep;
    ex[2 * t + 1] = ep + a0;

    const int node0 = b * 512;
    int n0 = node0 + 2 * t, n1 = node0 + 2 * t + 1;
    if (n0 < N_NODES) { off[k * N_NODES + n0] = beg + ep;      num[k * N_NODES + n0] = a0; }
    if (n1 < N_NODES) { off[k * N_NODES + n1] = beg + ep + a0; num[k * N_NODES + n1] = a1; }

    for (int i = t; i < 512; i += 256) nh[i] = 0;   // reuse as cursor
    __syncthreads();
    for (int i = beg + t; i < end; i += 256) {
        uint2 e = binned[i];
        int dl = (e.y >> 16) & 511;
        int pos = beg + ex[dl] + atomicAdd(&nh[dl], 1);
        csr4[pos] = (e.y & 0xFFFFu) | (f2bf(__uint_as_float(e.x)) << 16);
    }
}

// ---------------- merged gather: one node per 32-lane half-wave, all 3 k's ----------------
__global__ __launch_bounds__(256) void gather_all(const unsigned* __restrict__ h3,
                                                  const unsigned* __restrict__ csr4,
                                                  const int* __restrict__ off,
                                                  const int* __restrict__ num,
                                                  float* __restrict__ out) {
    const int half = threadIdx.x >> 5;               // 0..7
    const int l = threadIdx.x & 31;
    const int node = blockIdx.x * 8 + half;
    if (node >= N_NODES) return;

    float a0 = 0.f, a1 = 0.f, a2 = 0.f, a3 = 0.f;
    #pragma unroll
    for (int k = 0; k < KCHEB; ++k) {
        const unsigned* h2 = h3 + (size_t)k * N_NODES * 64;
        const int kd = k * N_NODES + node;
        int i = off[kd];
        const int end = i + num[kd];
        for (; i + 8 <= end; i += 8) {
            unsigned e[8];
            uint2 u[8];
            #pragma unroll
            for (int j = 0; j < 8; ++j) e[j] = csr4[i + j];
            #pragma unroll
            for (int j = 0; j < 8; ++j)
                u[j] = *(const uint2*)&h2[(size_t)(e[j] & 0xFFFFu) * 64 + l * 2];
            #pragma unroll
            for (int j = 0; j < 8; ++j) {
                float w = __uint_as_float(e[j] & 0xFFFF0000u);
                a0 += w * __uint_as_float(u[j].x << 16);
                a1 += w * __uint_as_float(u[j].x & 0xFFFF0000u);
                a2 += w * __uint_as_float(u[j].y << 16);
                a3 += w * __uint_as_float(u[j].y & 0xFFFF0000u);
            }
        }
        for (; i < end; ++i) {
            unsigned e = csr4[i];
            float w = __uint_as_float(e & 0xFFFF0000u);
            uint2 u = *(const uint2*)&h2[(size_t)(e & 0xFFFFu) * 64 + l * 2];
            a0 += w * __uint_as_float(u.x << 16);
            a1 += w * __uint_as_float(u.x & 0xFFFF0000u);
            a2 += w * __uint_as_float(u.y << 16);
            a3 += w * __uint_as_float(u.y & 0xFFFF0000u);
        }
    }
    *(float4*)&out[(size_t)node * D + l * 4] = make_float4(a0, a1, a2, a3);
}

extern "C" void kernel_launch(void* const* d_in, const int* in_sizes, int n_in,
                              void* d_out, int out_size, void* d_ws, size_t ws_size,
                              hipStream_t stream) {
    const float* x  = (const float*)d_in[0];
    const float* W  = (const float*)d_in[1];
    const int*   ei = (const int*)d_in[2];
    const float* ew = (const float*)d_in[3];
    float* out = (float*)d_out;

    // workspace layout (bytes) — ws_size = 256 MiB
    char* ws = (char*)d_ws;
    unsigned*       csr4   = (unsigned*)      (ws);                // 294*16384*4 = 19,267,584
    uint2*          binned = (uint2*)         (ws + 19267584);     // 38,535,168
    unsigned*       h3     = (unsigned*)      (ws + 57802752);     // 38,400,000
    int*            off    = (int*)           (ws + 96202752);     //    600,000
    int*            num    = (int*)           (ws + 96802752);     //    600,000
    int*            cursor = (int*)           (ws + 97402752);     //      1,176
    unsigned short* Wtg    = (unsigned short*)(ws + 97403936);     //     98,304

    hipMemsetAsync(cursor, 0, TOTB * sizeof(int), stream);

    wprep<<<KCHEB, 256, 0, stream>>>(W, Wtg);

    const dim3 egrid(NBLK_E, KCHEB);                        // (391, 3)
    bucket_bin<<<egrid, 256, 0, stream>>>(ei, ew, cursor, binned);

    const dim3 ggrid((N_NODES + 63) / 64, KCHEB);           // (782, 3)
    gemm_mfma<<<ggrid, 256, 0, stream>>>(x, Wtg, h3, N_NODES);

    build_csr<<<TOTB, 256, 0, stream>>>(binned, cursor, off, num, csr4);

    const int gat_grid = (N_NODES + 7) / 8;                 // 6250
    gather_all<<<gat_grid, 256, 0, stream>>>(h3, csr4, off, num, out);
}